// Round 2
// baseline (376.589 us; speedup 1.0000x reference)
//
#include <hip/hip_runtime.h>
#include <stdint.h>
#include <type_traits>

typedef __bf16 bf16;
typedef _Float16 f16;
typedef bf16 bf16x8 __attribute__((ext_vector_type(8)));
typedef f16 f16x8 __attribute__((ext_vector_type(8)));
typedef float f32x4 __attribute__((ext_vector_type(4)));

#define LOG2E 1.4426950408889634f
#define SQRT_E 27.712812921102035f

enum { EPI_F32 = 0, EPI_PAIR = 1, EPI_VT = 2, EPI_F16 = 3 };

__device__ __forceinline__ void async16(const void* g, void* l) {
  __builtin_amdgcn_global_load_lds(
      (__attribute__((address_space(1))) void*)(uintptr_t)g,
      (__attribute__((address_space(3))) void*)l, 16, 0, 0);
}

__device__ __forceinline__ f32x4 mfma8(bf16x8 a, bf16x8 b, f32x4 c) {
  return __builtin_amdgcn_mfma_f32_16x16x32_bf16(a, b, c, 0, 0, 0);
}
__device__ __forceinline__ f32x4 mfma8(f16x8 a, f16x8 b, f32x4 c) {
  return __builtin_amdgcn_mfma_f32_16x16x32_f16(a, b, c, 0, 0, 0);
}

template <int N>
__device__ __forceinline__ void vwait() {
  asm volatile("s_waitcnt vmcnt(%0)" ::"i"(N) : "memory");
}
__device__ __forceinline__ void block_bar() {
  asm volatile("" ::: "memory");
  __builtin_amdgcn_s_barrier();
  asm volatile("" ::: "memory");
}

// ---------------------------------------------------------------------------
// Pipelined GEMM: C[M,N] = A[M,K]*B[N,K]^T, double-buffered LDS with counted
// vmcnt (T3+T4). Schedule per K-tile t:
//   compute(buf[t&1]);               // ds_read + MFMA (compiler lgkmcnt)
//   barrier;                         // all waves done reading buf[t&1]
//   stage(t+2 -> buf[t&1]);          // async loads, land under next compute
//   vmcnt(LPT);                      // tile t+1 landed; t+2 stays in flight
//   barrier;                         // t+1 visible to all waves
// Race-freedom: stage into a buffer only after the barrier that ends its
// reads; vmcnt(LPT)+barrier makes t+1 globally visible before it is read.
// BK=64 rows (128B) use the proven XOR swizzle (pre-swizzled global source,
// same involution on ds_read). BK=32 rows (64B) are natively 2-way-free.
// ---------------------------------------------------------------------------
template <typename T, typename TO, int BMt, int BNt, int BKt, int AT, int EPI>
__global__ __launch_bounds__((BMt == 256 ? 512 : 256), 2)
void gemm_pipe(const T* __restrict__ Ah, const T* __restrict__ Al,
               const T* __restrict__ Bh, void* __restrict__ C0,
               int K, long lda, long ldb, long ldc,
               long stA, long stB, long stC, int gxN, int gyM) {
  using vec8 = typename std::conditional<std::is_same<T, bf16>::value,
                                         bf16x8, f16x8>::type;
  static_assert(BMt == BNt, "square tiles only");
  constexpr int THREADS = (BMt == 256) ? 512 : 256;
  constexpr int NWN = (BMt == 256) ? 4 : 2;       // wave grid 2 x NWN
  constexpr int WTM = BMt / 2;                    // per-wave rows
  constexpr int WTN = BNt / NWN;                  // per-wave cols (=64)
  static_assert(WTN == 64, "wave tile must be 64 wide");
  constexpr int MF = WTM / 16;                    // M fragments per wave
  constexpr int KK = BKt / 32;                    // k sub-steps per tile
  constexpr int CPR = BKt / 8;                    // 16B chunks per LDS row
  constexpr int RPI = THREADS / CPR;              // rows per load instr
  constexpr int LPP = (BMt * BKt) / (THREADS * 8);  // loads/thread/plane
  constexpr int LPT = LPP * (AT == 2 ? 3 : 2);    // loads/thread/K-tile

  __shared__ __align__(16) T sA[2][BMt * BKt];
  __shared__ __align__(16) T sB[2][BNt * BKt];
  __shared__ __align__(16) T sAl[AT == 2 ? 2 * BMt * BKt : 8];

  // XCD-aware 1D decode (all pipelined launches are swizzled)
  const int id = blockIdx.x;
  const int xcd = id & 7;
  const int j0 = id >> 3;
  const int s = j0 / gxN;
  const int bxi = j0 - s * gxN;
  const int g = xcd + 8 * s;
  const int byi = g % gyM;
  const int z = g / gyM;

  const T* pA = Ah + (long)z * stA;
  const T* pB = Bh + (long)z * stB;
  const T* pAl = (AT == 2) ? Al : nullptr;  // 2-term uses have no batch

  const int bm = byi * BMt;
  const int bn = bxi * BNt;
  const int tid = threadIdx.x;
  const int wave = tid >> 6;
  const int lane = tid & 63;
  const int wm = (wave / NWN) * WTM;
  const int wn = (wave % NWN) * WTN;
  const int quad = lane >> 4;
  const int l16 = lane & 15;

  f32x4 acc[MF][4] = {};

  const int srow = tid / CPR;   // staging row within a load-group
  const int schk = tid % CPR;   // staging 16B chunk within row
  const int swc = ((BKt == 64) ? (schk ^ (srow & 7)) : schk) * 8;
  const int cs0 = (quad * 8) ^ ((BKt == 64) ? ((l16 & 7) << 3) : 0);

  const int NT = K / BKt;

  auto stage = [&](int buf, int t) {
    const long ka = (long)t * BKt + swc;
#pragma unroll
    for (int l = 0; l < LPP; ++l)
      async16(pA + (long)(bm + l * RPI + srow) * lda + ka,
              &sA[buf][(l * THREADS + tid) * 8]);
#pragma unroll
    for (int l = 0; l < LPP; ++l)
      async16(pB + (long)(bn + l * RPI + srow) * ldb + ka,
              &sB[buf][(l * THREADS + tid) * 8]);
    if constexpr (AT == 2) {
#pragma unroll
      for (int l = 0; l < LPP; ++l)
        async16(pAl + (long)(bm + l * RPI + srow) * lda + ka,
                &sAl[buf * BMt * BKt + (l * THREADS + tid) * 8]);
    }
  };

  auto compute = [&](int buf) {
    const T* bA = &sA[buf][0];
    const T* bB = &sB[buf][0];
    const T* bAl = (AT == 2) ? &sAl[buf * BMt * BKt] : nullptr;
    vec8 bf[KK][4];
#pragma unroll
    for (int kk = 0; kk < KK; ++kk)
#pragma unroll
      for (int jj = 0; jj < 4; ++jj)
        bf[kk][jj] =
            *(const vec8*)&bB[(wn + jj * 16 + l16) * BKt + (cs0 ^ (kk * 32))];
#pragma unroll
    for (int mq = 0; mq < MF / 2; ++mq) {
      vec8 af[KK][2];
      vec8 alf[AT == 2 ? KK : 1][2];
#pragma unroll
      for (int kk = 0; kk < KK; ++kk)
#pragma unroll
        for (int ii = 0; ii < 2; ++ii) {
          const int r = wm + mq * 32 + ii * 16 + l16;
          af[kk][ii] = *(const vec8*)&bA[r * BKt + (cs0 ^ (kk * 32))];
          if constexpr (AT == 2)
            alf[kk][ii] = *(const vec8*)&bAl[r * BKt + (cs0 ^ (kk * 32))];
        }
      __builtin_amdgcn_s_setprio(1);
#pragma unroll
      for (int jj = 0; jj < 4; ++jj)
#pragma unroll
        for (int ii = 0; ii < 2; ++ii)
#pragma unroll
          for (int kk = 0; kk < KK; ++kk) {
            acc[mq * 2 + ii][jj] =
                mfma8(af[kk][ii], bf[kk][jj], acc[mq * 2 + ii][jj]);
            if constexpr (AT == 2)
              acc[mq * 2 + ii][jj] =
                  mfma8(alf[kk][ii], bf[kk][jj], acc[mq * 2 + ii][jj]);
          }
      __builtin_amdgcn_s_setprio(0);
    }
  };

  // prologue: tiles 0,1 in flight; wait tile 0 only
  stage(0, 0);
  stage(1, 1);
  vwait<LPT>();
  block_bar();

  for (int t = 0; t < NT; ++t) {
    const int cur = t & 1;
    compute(cur);
    if (t + 1 < NT) {
      block_bar();
      if (t + 2 < NT) {
        stage(cur, t + 2);
        vwait<LPT>();
      } else {
        vwait<0>();
      }
      block_bar();
    }
  }

  // C/D frag mapping (m89/m91 verified): col = lane&15, row = quad*4 + reg
  if constexpr (EPI == EPI_F32) {
    float* C = (float*)C0 + (long)z * stC;
#pragma unroll
    for (int i = 0; i < MF; ++i) {
      const int mb = bm + wm + i * 16 + quad * 4;
#pragma unroll
      for (int j = 0; j < 4; ++j) {
        const int n = bn + wn + j * 16 + l16;
#pragma unroll
        for (int r = 0; r < 4; ++r)
          C[(long)(mb + r) * ldc + n] = acc[i][j][r];
      }
    }
  } else if constexpr (EPI == EPI_F16) {
    TO* Ch = (TO*)C0;
#pragma unroll
    for (int i = 0; i < MF; ++i) {
      const int mb = bm + wm + i * 16 + quad * 4;
#pragma unroll
      for (int j = 0; j < 4; ++j) {
        const int n = bn + wn + j * 16 + l16;
#pragma unroll
        for (int r = 0; r < 4; ++r)
          Ch[(long)(mb + r) * ldc + n] = (TO)acc[i][j][r];
      }
    }
  } else {  // EPI_VT: C0 = vT [8][768][2048], global row m -> (m>>11, m&2047)
    TO* vT = (TO*)C0;
#pragma unroll
    for (int i = 0; i < MF; ++i) {
      const int mb = bm + wm + i * 16 + quad * 4;
      const long bb = mb >> 11;
      const long ml = mb & 2047;
#pragma unroll
      for (int j = 0; j < 4; ++j) {
        const int e = bn + wn + j * 16 + l16;
        union { TO b[4]; uint2 u; } P;
#pragma unroll
        for (int r = 0; r < 4; ++r) P.b[r] = (TO)acc[i][j][r];
        *(uint2*)&vT[(bb * 768 + e) * 2048 + ml] = P.u;
      }
    }
  }
}

// ---------------------------------------------------------------------------
// Old 128x128/BK64 kernel (verified) — kept for the small Mt GEMM only.
// ---------------------------------------------------------------------------
constexpr int BM = 128, BN = 128, BK = 64;

template <typename T, typename TO, int AT, int BT, int EPI, int SWZ>
__global__ __launch_bounds__(256)
void gemm_kernel(const T* __restrict__ Ah, const T* __restrict__ Al,
                 const T* __restrict__ Bh, const T* __restrict__ Bl,
                 void* __restrict__ C0, void* __restrict__ C1,
                 int K, long lda, long ldb, long ldbl, long ldc,
                 long stA, long stB, long stBl, long stC,
                 int gxN, int gyM) {
  using vec8 = typename std::conditional<std::is_same<T, bf16>::value,
                                         bf16x8, f16x8>::type;
  __shared__ __align__(16) T sAh[BM * BK];
  __shared__ __align__(16) T sBh[BN * BK];
  __shared__ __align__(16) T sAl[AT == 2 ? BM * BK : 8];
  __shared__ __align__(16) T sBl[BT == 2 ? BN * BK : 8];

  int bxi, byi, z;
  if constexpr (SWZ) {
    const int id = blockIdx.x;
    const int xcd = id & 7;
    const int j = id >> 3;
    const int s = j / gxN;
    const int n = j - s * gxN;
    const int g = xcd + 8 * s;
    bxi = n;
    byi = g % gyM;
    z = g / gyM;
  } else {
    bxi = blockIdx.x; byi = blockIdx.y; z = blockIdx.z;
  }

  const T* pAh = Ah + (long)z * stA;
  const T* pBh = Bh + (long)z * stB;
  const T* pAl = (AT == 2) ? (Al + (long)z * stA) : nullptr;
  const T* pBl = (BT == 2) ? (Bl + (long)z * stBl) : nullptr;

  const int bm = byi * BM;
  const int bn = bxi * BN;
  const int tid = threadIdx.x;
  const int wave = tid >> 6;
  const int lane = tid & 63;
  const int wm = (wave & 1) * 64;
  const int wn = (wave >> 1) * 64;
  const int quad = lane >> 4;
  const int l16 = lane & 15;

  f32x4 acc[4][4] = {};

  const int sr0 = tid >> 3;
  const int swc = ((tid & 7) ^ (sr0 & 7)) * 8;
  const int cs0 = (quad * 8) ^ ((l16 & 7) << 3);

  for (int kt = 0; kt < K; kt += BK) {
    __syncthreads();
    {
      const long ka = kt + swc;
#pragma unroll
      for (int l = 0; l < 4; ++l) {
        const int row = l * 32 + sr0;
        async16(pAh + (long)(bm + row) * lda + ka, &sAh[(l * 256 + tid) * 8]);
      }
#pragma unroll
      for (int l = 0; l < 4; ++l) {
        const int row = l * 32 + sr0;
        async16(pBh + (long)(bn + row) * ldb + ka, &sBh[(l * 256 + tid) * 8]);
      }
      if constexpr (AT == 2) {
#pragma unroll
        for (int l = 0; l < 4; ++l) {
          const int row = l * 32 + sr0;
          async16(pAl + (long)(bm + row) * lda + ka, &sAl[(l * 256 + tid) * 8]);
        }
      }
      if constexpr (BT == 2) {
#pragma unroll
        for (int l = 0; l < 4; ++l) {
          const int row = l * 32 + sr0;
          async16(pBl + (long)(bn + row) * ldbl + ka, &sBl[(l * 256 + tid) * 8]);
        }
      }
    }
    __syncthreads();

#pragma unroll
    for (int kk = 0; kk < 2; ++kk) {
      const int cs = cs0 ^ (kk * 32);
      vec8 ah[4], al[4];
#pragma unroll
      for (int i = 0; i < 4; ++i) {
        ah[i] = *(const vec8*)&sAh[(wm + i * 16 + l16) * BK + cs];
        if constexpr (AT == 2)
          al[i] = *(const vec8*)&sAl[(wm + i * 16 + l16) * BK + cs];
      }
#pragma unroll
      for (int j = 0; j < 4; ++j) {
        const vec8 bh = *(const vec8*)&sBh[(wn + j * 16 + l16) * BK + cs];
        vec8 bl;
        if constexpr (BT == 2)
          bl = *(const vec8*)&sBl[(wn + j * 16 + l16) * BK + cs];
#pragma unroll
        for (int i = 0; i < 4; ++i) {
          acc[i][j] = mfma8(ah[i], bh, acc[i][j]);
          if constexpr (BT == 2) acc[i][j] = mfma8(ah[i], bl, acc[i][j]);
          if constexpr (AT == 2) acc[i][j] = mfma8(al[i], bh, acc[i][j]);
        }
      }
    }
  }

  if constexpr (EPI == EPI_PAIR) {
    TO* Ch = (TO*)C0;
    TO* Cl = (TO*)C1;
#pragma unroll
    for (int i = 0; i < 4; ++i) {
      const int mb = bm + wm + i * 16 + quad * 4;
#pragma unroll
      for (int j = 0; j < 4; ++j) {
        const int n = bn + wn + j * 16 + l16;
#pragma unroll
        for (int r = 0; r < 4; ++r) {
          const float f = acc[i][j][r];
          const TO h = (TO)f;
          const long idx = (long)(mb + r) * ldc + n;
          Ch[idx] = h;
          Cl[idx] = (TO)(f - (float)h);
        }
      }
    }
  }
}

// One block per score row (2048 fp32). Writes normalized p * (1/sqrt(768)) as
// f16 IN-PLACE into the first quarter of the row's fp32 storage.
__global__ __launch_bounds__(256)
void softmax_kernel(float* __restrict__ sc) {
  __shared__ float red[4];
  float* srow = sc + (long)blockIdx.x * 2048;
  const int tid = threadIdx.x;
  const int wave = tid >> 6;
  const int lane = tid & 63;
  const float4 v0 = *(const float4*)(srow + tid * 4);
  const float4 v1 = *(const float4*)(srow + 1024 + tid * 4);
  float mx = fmaxf(fmaxf(fmaxf(v0.x, v0.y), fmaxf(v0.z, v0.w)),
                   fmaxf(fmaxf(v1.x, v1.y), fmaxf(v1.z, v1.w)));
#pragma unroll
  for (int o = 32; o >= 1; o >>= 1) mx = fmaxf(mx, __shfl_xor(mx, o));
  if (lane == 0) red[wave] = mx;
  __syncthreads();
  mx = fmaxf(fmaxf(red[0], red[1]), fmaxf(red[2], red[3]));
  const float e0 = exp2f((v0.x - mx) * LOG2E);
  const float e1 = exp2f((v0.y - mx) * LOG2E);
  const float e2 = exp2f((v0.z - mx) * LOG2E);
  const float e3 = exp2f((v0.w - mx) * LOG2E);
  const float e4 = exp2f((v1.x - mx) * LOG2E);
  const float e5 = exp2f((v1.y - mx) * LOG2E);
  const float e6 = exp2f((v1.z - mx) * LOG2E);
  const float e7 = exp2f((v1.w - mx) * LOG2E);
  float s = ((e0 + e1) + (e2 + e3)) + ((e4 + e5) + (e6 + e7));
#pragma unroll
  for (int o = 32; o >= 1; o >>= 1) s += __shfl_xor(s, o);
  __syncthreads();
  if (lane == 0) red[wave] = s;
  __syncthreads();
  s = red[0] + red[1] + red[2] + red[3];
  const float inv = 1.0f / (s * SQRT_E);
  f16* prow = (f16*)srow;
  union { f16 b[4]; uint2 u; } P;
  P.b[0] = (f16)(e0 * inv); P.b[1] = (f16)(e1 * inv);
  P.b[2] = (f16)(e2 * inv); P.b[3] = (f16)(e3 * inv);
  *(uint2*)(prow + tid * 4) = P.u;
  P.b[0] = (f16)(e4 * inv); P.b[1] = (f16)(e5 * inv);
  P.b[2] = (f16)(e6 * inv); P.b[3] = (f16)(e7 * inv);
  *(uint2*)(prow + 1024 + tid * 4) = P.u;
}

// Fused fp32 -> f16: x -> hi/lo pair; Wv -> single.
__global__ __launch_bounds__(256)
void split_all(const float4* __restrict__ x, const float4* __restrict__ wv,
               uint2* __restrict__ xh, uint2* __restrict__ xl,
               uint2* __restrict__ wvh) {
  constexpr int NX = 3145728;
  constexpr int NWV = 147456;
  const int i = blockIdx.x * 256 + threadIdx.x;
  float4 v;
  uint2 *dh, *dl;
  if (i < NX) {
    v = x[i]; dh = xh + i; dl = xl + i;
  } else {
    const int m = i - NX;
    if (m >= NWV) return;
    v = wv[m]; dh = wvh + m; dl = nullptr;
  }
  const f16 h0 = (f16)v.x, h1 = (f16)v.y, h2 = (f16)v.z, h3 = (f16)v.w;
  union { f16 b[4]; uint2 u; } P;
  P.b[0] = h0; P.b[1] = h1; P.b[2] = h2; P.b[3] = h3;
  *dh = P.u;
  if (dl != nullptr) {
    P.b[0] = (f16)(v.x - (float)h0);
    P.b[1] = (f16)(v.y - (float)h1);
    P.b[2] = (f16)(v.z - (float)h2);
    P.b[3] = (f16)(v.w - (float)h3);
    *dl = P.u;
  }
}

// Transpose 768x768 fp32 W[e][d] -> f16 hi/lo pair WT[d][e] (e contiguous).
__global__ __launch_bounds__(256)
void transpose_split(const float* __restrict__ Wq, const float* __restrict__ Wk,
                     f16* __restrict__ qTh, f16* __restrict__ qTl,
                     f16* __restrict__ kTh, f16* __restrict__ kTl) {
  __shared__ float tile[64][65];
  const float* src = blockIdx.z ? Wk : Wq;
  f16* dh = blockIdx.z ? kTh : qTh;
  f16* dl = blockIdx.z ? kTl : qTl;
  const int e0 = blockIdx.y * 64, d0 = blockIdx.x * 64;
  const int t = threadIdx.x;
  const int r = t >> 2;
  const int c4 = (t & 3) * 16;
  const float4* s4 = (const float4*)(src + (long)(e0 + r) * 768 + d0 + c4);
#pragma unroll
  for (int g = 0; g < 4; ++g) {
    const float4 v = s4[g];
    tile[r][c4 + g * 4 + 0] = v.x;
    tile[r][c4 + g * 4 + 1] = v.y;
    tile[r][c4 + g * 4 + 2] = v.z;
    tile[r][c4 + g * 4 + 3] = v.w;
  }
  __syncthreads();
  union { f16 b[8]; uint4 u; } H0, H1, L0, L1;
#pragma unroll
  for (int i = 0; i < 16; ++i) {
    const float v = tile[c4 + i][r];
    const f16 h = (f16)v;
    const f16 l = (f16)(v - (float)h);
    if (i < 8) { H0.b[i] = h; L0.b[i] = l; }
    else       { H1.b[i - 8] = h; L1.b[i - 8] = l; }
  }
  const long o = (long)(d0 + r) * 768 + e0 + c4;
  *(uint4*)(dh + o) = H0.u;  *(uint4*)(dh + o + 8) = H1.u;
  *(uint4*)(dl + o) = L0.u;  *(uint4*)(dl + o + 8) = L1.u;
}

extern "C" void kernel_launch(void* const* d_in, const int* in_sizes, int n_in,
                              void* d_out, int out_size, void* d_ws, size_t ws_size,
                              hipStream_t stream) {
  const float* x  = (const float*)d_in[0];
  const float* Wq = (const float*)d_in[1];
  const float* Wk = (const float*)d_in[2];
  const float* Wv = (const float*)d_in[3];
  float* out = (float*)d_out;
  char* ws = (char*)d_ws;

  // ---- workspace layout (bytes) ----
  const size_t SZ = 25165824;      // 16384*768*2
  f16* yh = (f16*)(ws + 0 * SZ);
  f16* xh = (f16*)(ws + 2 * SZ);
  f16* vT = (f16*)(ws + 3 * SZ);
  const size_t PERS = 4 * SZ;      // 100663296
  const size_t WT = 1179648;       // 768*768 f16
  f16* xl   = (f16*)(ws + PERS);
  f16* wqTh = (f16*)(ws + PERS + SZ);
  f16* wqTl = (f16*)(ws + PERS + SZ + 1 * WT);
  f16* wkTh = (f16*)(ws + PERS + SZ + 2 * WT);
  f16* wkTl = (f16*)(ws + PERS + SZ + 3 * WT);
  f16* mtH  = (f16*)(ws + PERS + SZ + 4 * WT);
  f16* mtL  = (f16*)(ws + PERS + SZ + 5 * WT);
  f16* wvh  = (f16*)(ws + PERS + SZ + 6 * WT);
  float* scores = (float*)(ws + PERS);

  long avail = (long)ws_size - (long)PERS;
  int nb = (int)(avail / 16777216);
  if (nb < 1) nb = 1;
  if (nb > 8) nb = 8;

  // ---- phase 1 ----
  split_all<<<12864, 256, 0, stream>>>(
      (const float4*)x, (const float4*)Wv, (uint2*)xh, (uint2*)xl, (uint2*)wvh);
  transpose_split<<<dim3(12, 12, 2), 256, 0, stream>>>(
      Wq, Wk, wqTh, wqTl, wkTh, wkTl);

  // M^T[d'][d] = sum_e WkT[d'][e] * WqT[d][e]  (3-term, f16 pair out)
  gemm_kernel<f16, f16, 2, 2, EPI_PAIR, 0><<<dim3(6, 6, 1), 256, 0, stream>>>(
      wkTh, wkTl, wqTh, wqTl, (void*)mtH, (void*)mtL,
      768, 768, 768, 768, 768, 0, 0, 0, 0, 0, 0);

  // y = (xh+xl) * MT_h^T : f16 hi only, 2-term, BK32 dbuf (3 blk/CU)
  gemm_pipe<f16, f16, 128, 128, 32, 2, EPI_F16><<<768, 256, 0, stream>>>(
      xh, xl, mtH, (void*)yh, 768, 768, 768, 768, 0, 0, 0, 6, 128);

  // v = xh * Wv_h^T -> vT f16 transposed, 1-term, BK64 dbuf
  gemm_pipe<f16, f16, 128, 128, 64, 1, EPI_VT><<<768, 256, 0, stream>>>(
      xh, nullptr, wvh, (void*)vT, 768, 768, 768, 0, 0, 0, 0, 6, 128);

  // ---- phase 2: scores -> softmax -> PV ----
  const long RS = 1572864;   // 2048*768
  const long VTS = 1572864;  // 768*2048
  for (int b0 = 0; b0 < 8; b0 += nb) {
    const int nbg = (8 - b0 < nb) ? (8 - b0) : nb;
    // S = yh * xh^T : 256^2 tile, 512 thr, 64 MFMA per barrier-pair
    gemm_pipe<f16, float, 256, 256, 64, 1, EPI_F32><<<64 * nbg, 512, 0, stream>>>(
        yh + (long)b0 * RS, nullptr, xh + (long)b0 * RS, (void*)scores,
        768, 768, 768, 2048, RS, RS, 4194304L, 8, 8);
    softmax_kernel<<<nbg * 2048, 256, 0, stream>>>(scores);
    // O = P * vT^T (P f16 rows in fp32 score rows, pitch 4096 elems)
    gemm_pipe<f16, float, 128, 128, 64, 1, EPI_F32><<<96 * nbg, 256, 0, stream>>>(
        (const f16*)scores, nullptr, vT + (long)b0 * VTS,
        (void*)(out + (long)b0 * 1572864),
        2048, 4096, 2048, 768, 8388608L, VTS, 1572864L, 6, 16);
  }
}

// Round 3
// 366.115 us; speedup vs baseline: 1.0286x; 1.0286x over previous
//
#include <hip/hip_runtime.h>
#include <stdint.h>
#include <type_traits>

typedef __bf16 bf16;
typedef _Float16 f16;
typedef bf16 bf16x8 __attribute__((ext_vector_type(8)));
typedef f16 f16x8 __attribute__((ext_vector_type(8)));
typedef float f32x4 __attribute__((ext_vector_type(4)));

#define LOG2E 1.4426950408889634f
#define SQRT_E 27.712812921102035f

enum { EPI_F32 = 0, EPI_PAIR = 1, EPI_VT = 2, EPI_F16 = 3 };

__device__ __forceinline__ void async16(const void* g, void* l) {
  __builtin_amdgcn_global_load_lds(
      (__attribute__((address_space(1))) void*)(uintptr_t)g,
      (__attribute__((address_space(3))) void*)l, 16, 0, 0);
}

__device__ __forceinline__ f32x4 mfma8(bf16x8 a, bf16x8 b, f32x4 c) {
  return __builtin_amdgcn_mfma_f32_16x16x32_bf16(a, b, c, 0, 0, 0);
}
__device__ __forceinline__ f32x4 mfma8(f16x8 a, f16x8 b, f32x4 c) {
  return __builtin_amdgcn_mfma_f32_16x16x32_f16(a, b, c, 0, 0, 0);
}

template <int N>
__device__ __forceinline__ void vwait() {
  asm volatile("s_waitcnt vmcnt(%0)" ::"i"(N) : "memory");
}
__device__ __forceinline__ void block_bar() {
  asm volatile("" ::: "memory");
  __builtin_amdgcn_s_barrier();
  asm volatile("" ::: "memory");
}
__device__ __forceinline__ void lgkm0() {
  asm volatile("s_waitcnt lgkmcnt(0)" ::: "memory");
}
__device__ __forceinline__ void spin() { __builtin_amdgcn_sched_barrier(0); }

// ---------------------------------------------------------------------------
// Fine-phase ring GEMM (T3+T4+T5 port): C[M,N] = A[M,K]*B[N,K]^T.
// 256x256 tile, BK=32, 512 threads (8 waves as 2Mx4N, wave tile 128x64),
// 3-buffer LDS ring (96 KB 1-term). Iteration t:
//   P0: ds_read A-frags Mf0-3 + B-frags (8 b128) ; stage 2 loads of tile t+2
//       BAR ; lgkmcnt(0) ; setprio(1) ; 16 MFMA ; setprio(0) ; BAR
//   P1: ds_read A-frags Mf4-7 (4 b128) ; stage 2 loads of tile t+2
//       BAR ; lgkmcnt(0) ; setprio(1) ; 16 MFMA ; setprio(0) ; vmcnt(4) ; BAR
// Race-freedom: buf (t+2)%3 was last read in iter t-1 (reads fenced by its
// last barrier); vmcnt(4) at iter end leaves only tile t+2's 4 loads in
// flight => tile t+1 landed before any wave reads it (barrier follows).
// BK=32 rows (64 B, 4 chunks) are 8-way-conflicted raw; both-sides XOR
// swizzle chunk ^= (row>>1)&3 makes every quad-cycle 2-way (free).
// z-major decode (nz>0): each XCD owns one batch -> B-panel fits its L2.
// ---------------------------------------------------------------------------
template <typename T, typename TO, int AT, int EPI>
__global__ __launch_bounds__(512, 2)
void gemm_ring(const T* __restrict__ Ah, const T* __restrict__ Al,
               const T* __restrict__ Bh, void* __restrict__ C0,
               int K, long lda, long ldb, long ldc,
               long stA, long stB, long stC, int gxN, int gyM, int nz) {
  using vec8 = typename std::conditional<std::is_same<T, bf16>::value,
                                         bf16x8, f16x8>::type;
  constexpr int LPT = (AT == 2) ? 6 : 4;   // staged loads/thread/tile
  __shared__ __align__(16) T sA[3][256 * 32];
  __shared__ __align__(16) T sB[3][256 * 32];
  __shared__ __align__(16) T sAl[AT == 2 ? 3 * 256 * 32 : 8];

  const int id = blockIdx.x;
  const int xcd = id & 7;
  const int j0 = id >> 3;
  const int s = j0 / gxN;
  const int bxi = j0 - s * gxN;
  const int g = xcd + 8 * s;
  int byi, z;
  if (nz > 0) { z = g % nz; byi = g / nz; }
  else        { byi = g % gyM; z = g / gyM; }

  const T* pA = Ah + (long)z * stA;
  const T* pB = Bh + (long)z * stB;
  const T* pAl = (AT == 2) ? Al : nullptr;

  const int bm = byi * 256;
  const int bn = bxi * 256;
  const int tid = threadIdx.x;
  const int wave = tid >> 6;
  const int lane = tid & 63;
  const int wm = (wave >> 2) * 128;   // 2 wave-rows
  const int wn = (wave & 3) * 64;     // 4 wave-cols
  const int quad = lane >> 4;
  const int l16 = lane & 15;

  f32x4 acc[8][4] = {};

  // staging: thread t -> LDS chunk q = l*512+tid (linear), logical row q>>2,
  // chunk q&3. Swizzled global chunk = (tid&3) ^ ((tid>>3)&3)  (row>>1 == tid>>3
  // mod 4 since each load-group starts at a row multiple of 128).
  const int srow = tid >> 2;                        // 0..127
  const int swc = ((tid & 3) ^ ((tid >> 3) & 3)) * 8;
  // read: frag rows are (multiple of 16) + l16 -> (row>>1)&3 == (l16>>1)&3
  const int cread = (quad ^ ((l16 >> 1) & 3)) * 8;

  const int NT = K / 32;

  auto stageA = [&](int buf, int t, int l) {
    const long ka = (long)t * 32 + swc;
    async16(pA + (long)(bm + l * 128 + srow) * lda + ka,
            &sA[buf][(l * 512 + tid) * 8]);
  };
  auto stageB = [&](int buf, int t, int l) {
    const long ka = (long)t * 32 + swc;
    async16(pB + (long)(bn + l * 128 + srow) * ldb + ka,
            &sB[buf][(l * 512 + tid) * 8]);
  };
  auto stageAl = [&](int buf, int t, int l) {
    const long ka = (long)t * 32 + swc;
    async16(pAl + (long)(bm + l * 128 + srow) * lda + ka,
            &sAl[buf * 8192 + (l * 512 + tid) * 8]);
  };

  // prologue: tiles 0,1 fully staged; wait tile 0 (tile 1 stays in flight)
  stageA(0, 0, 0); stageA(0, 0, 1); stageB(0, 0, 0); stageB(0, 0, 1);
  if constexpr (AT == 2) { stageAl(0, 0, 0); stageAl(0, 0, 1); }
  stageA(1, 1, 0); stageA(1, 1, 1); stageB(1, 1, 0); stageB(1, 1, 1);
  if constexpr (AT == 2) { stageAl(1, 1, 0); stageAl(1, 1, 1); }
  vwait<LPT>();
  block_bar();

  int cur = 0, b2 = 2;
  for (int t = 0; t < NT; ++t) {
    const bool st = (t + 2 < NT);
    // ---- phase 0: B-frags + A-frags Mf0-3 ----
    vec8 bfr[4], af[4], alf[AT == 2 ? 4 : 1];
#pragma unroll
    for (int j = 0; j < 4; ++j)
      bfr[j] = *(const vec8*)&sB[cur][(wn + j * 16 + l16) * 32 + cread];
#pragma unroll
    for (int i = 0; i < 4; ++i) {
      af[i] = *(const vec8*)&sA[cur][(wm + i * 16 + l16) * 32 + cread];
      if constexpr (AT == 2)
        alf[i] = *(const vec8*)&sAl[cur * 8192 + (wm + i * 16 + l16) * 32 + cread];
    }
    if (st) {
      stageA(b2, t + 2, 0); stageA(b2, t + 2, 1);
      if constexpr (AT == 2) stageAl(b2, t + 2, 0);
    }
    block_bar();
    lgkm0();
    spin();
    __builtin_amdgcn_s_setprio(1);
#pragma unroll
    for (int j = 0; j < 4; ++j)
#pragma unroll
      for (int i = 0; i < 4; ++i) {
        acc[i][j] = mfma8(af[i], bfr[j], acc[i][j]);
        if constexpr (AT == 2) acc[i][j] = mfma8(alf[i], bfr[j], acc[i][j]);
      }
    __builtin_amdgcn_s_setprio(0);
    spin();
    block_bar();
    // ---- phase 1: A-frags Mf4-7 ----
    vec8 af2[4], alf2[AT == 2 ? 4 : 1];
#pragma unroll
    for (int i = 0; i < 4; ++i) {
      af2[i] = *(const vec8*)&sA[cur][(wm + 64 + i * 16 + l16) * 32 + cread];
      if constexpr (AT == 2)
        alf2[i] =
            *(const vec8*)&sAl[cur * 8192 + (wm + 64 + i * 16 + l16) * 32 + cread];
    }
    if (st) {
      stageB(b2, t + 2, 0); stageB(b2, t + 2, 1);
      if constexpr (AT == 2) stageAl(b2, t + 2, 1);
    }
    block_bar();
    lgkm0();
    spin();
    __builtin_amdgcn_s_setprio(1);
#pragma unroll
    for (int j = 0; j < 4; ++j)
#pragma unroll
      for (int i = 0; i < 4; ++i) {
        acc[4 + i][j] = mfma8(af2[i], bfr[j], acc[4 + i][j]);
        if constexpr (AT == 2) acc[4 + i][j] = mfma8(alf2[i], bfr[j], acc[4 + i][j]);
      }
    __builtin_amdgcn_s_setprio(0);
    spin();
    if (t + 1 < NT) {
      if (st) vwait<LPT>(); else vwait<0>();
      block_bar();
    }
    cur = (cur == 2) ? 0 : cur + 1;
    b2 = (b2 == 2) ? 0 : b2 + 1;
  }

  // C/D frag mapping (m89/m91 verified): col = lane&15, row = quad*4 + reg
  if constexpr (EPI == EPI_F32) {
    float* C = (float*)C0 + (long)z * stC;
#pragma unroll
    for (int i = 0; i < 8; ++i) {
      const int mb = bm + wm + i * 16 + quad * 4;
#pragma unroll
      for (int j = 0; j < 4; ++j) {
        const int n = bn + wn + j * 16 + l16;
#pragma unroll
        for (int r = 0; r < 4; ++r)
          C[(long)(mb + r) * ldc + n] = acc[i][j][r];
      }
    }
  } else if constexpr (EPI == EPI_F16) {
    TO* Ch = (TO*)C0;
#pragma unroll
    for (int i = 0; i < 8; ++i) {
      const int mb = bm + wm + i * 16 + quad * 4;
#pragma unroll
      for (int j = 0; j < 4; ++j) {
        const int n = bn + wn + j * 16 + l16;
#pragma unroll
        for (int r = 0; r < 4; ++r)
          Ch[(long)(mb + r) * ldc + n] = (TO)acc[i][j][r];
      }
    }
  } else {  // EPI_VT
    TO* vT = (TO*)C0;
#pragma unroll
    for (int i = 0; i < 8; ++i) {
      const int mb = bm + wm + i * 16 + quad * 4;
      const long bb = mb >> 11;
      const long ml = mb & 2047;
#pragma unroll
      for (int j = 0; j < 4; ++j) {
        const int e = bn + wn + j * 16 + l16;
        union { TO b[4]; uint2 u; } P;
#pragma unroll
        for (int r = 0; r < 4; ++r) P.b[r] = (TO)acc[i][j][r];
        *(uint2*)&vT[(bb * 768 + e) * 2048 + ml] = P.u;
      }
    }
  }
}

// ---------------------------------------------------------------------------
// 2-phase pipelined GEMM (round-2, verified) — kept for y and v.
// ---------------------------------------------------------------------------
template <typename T, typename TO, int BMt, int BNt, int BKt, int AT, int EPI>
__global__ __launch_bounds__((BMt == 256 ? 512 : 256), 2)
void gemm_pipe(const T* __restrict__ Ah, const T* __restrict__ Al,
               const T* __restrict__ Bh, void* __restrict__ C0,
               int K, long lda, long ldb, long ldc,
               long stA, long stB, long stC, int gxN, int gyM) {
  using vec8 = typename std::conditional<std::is_same<T, bf16>::value,
                                         bf16x8, f16x8>::type;
  static_assert(BMt == BNt, "square tiles only");
  constexpr int THREADS = (BMt == 256) ? 512 : 256;
  constexpr int NWN = (BMt == 256) ? 4 : 2;
  constexpr int WTM = BMt / 2;
  constexpr int WTN = BNt / NWN;
  static_assert(WTN == 64, "wave tile must be 64 wide");
  constexpr int MF = WTM / 16;
  constexpr int KK = BKt / 32;
  constexpr int CPR = BKt / 8;
  constexpr int RPI = THREADS / CPR;
  constexpr int LPP = (BMt * BKt) / (THREADS * 8);
  constexpr int LPT = LPP * (AT == 2 ? 3 : 2);

  __shared__ __align__(16) T sA[2][BMt * BKt];
  __shared__ __align__(16) T sB[2][BNt * BKt];
  __shared__ __align__(16) T sAl[AT == 2 ? 2 * BMt * BKt : 8];

  const int id = blockIdx.x;
  const int xcd = id & 7;
  const int j0 = id >> 3;
  const int s = j0 / gxN;
  const int bxi = j0 - s * gxN;
  const int g = xcd + 8 * s;
  const int byi = g % gyM;
  const int z = g / gyM;

  const T* pA = Ah + (long)z * stA;
  const T* pB = Bh + (long)z * stB;
  const T* pAl = (AT == 2) ? Al : nullptr;

  const int bm = byi * BMt;
  const int bn = bxi * BNt;
  const int tid = threadIdx.x;
  const int wave = tid >> 6;
  const int lane = tid & 63;
  const int wm = (wave / NWN) * WTM;
  const int wn = (wave % NWN) * WTN;
  const int quad = lane >> 4;
  const int l16 = lane & 15;

  f32x4 acc[MF][4] = {};

  const int srow = tid / CPR;
  const int schk = tid % CPR;
  const int swc = ((BKt == 64) ? (schk ^ (srow & 7)) : schk) * 8;
  const int cs0 = (quad * 8) ^ ((BKt == 64) ? ((l16 & 7) << 3) : 0);

  const int NT = K / BKt;

  auto stage = [&](int buf, int t) {
    const long ka = (long)t * BKt + swc;
#pragma unroll
    for (int l = 0; l < LPP; ++l)
      async16(pA + (long)(bm + l * RPI + srow) * lda + ka,
              &sA[buf][(l * THREADS + tid) * 8]);
#pragma unroll
    for (int l = 0; l < LPP; ++l)
      async16(pB + (long)(bn + l * RPI + srow) * ldb + ka,
              &sB[buf][(l * THREADS + tid) * 8]);
    if constexpr (AT == 2) {
#pragma unroll
      for (int l = 0; l < LPP; ++l)
        async16(pAl + (long)(bm + l * RPI + srow) * lda + ka,
                &sAl[buf * BMt * BKt + (l * THREADS + tid) * 8]);
    }
  };

  auto compute = [&](int buf) {
    const T* bA = &sA[buf][0];
    const T* bB = &sB[buf][0];
    const T* bAl = (AT == 2) ? &sAl[buf * BMt * BKt] : nullptr;
    vec8 bf[KK][4];
#pragma unroll
    for (int kk = 0; kk < KK; ++kk)
#pragma unroll
      for (int jj = 0; jj < 4; ++jj)
        bf[kk][jj] =
            *(const vec8*)&bB[(wn + jj * 16 + l16) * BKt + (cs0 ^ (kk * 32))];
#pragma unroll
    for (int mq = 0; mq < MF / 2; ++mq) {
      vec8 af[KK][2];
      vec8 alf[AT == 2 ? KK : 1][2];
#pragma unroll
      for (int kk = 0; kk < KK; ++kk)
#pragma unroll
        for (int ii = 0; ii < 2; ++ii) {
          const int r = wm + mq * 32 + ii * 16 + l16;
          af[kk][ii] = *(const vec8*)&bA[r * BKt + (cs0 ^ (kk * 32))];
          if constexpr (AT == 2)
            alf[kk][ii] = *(const vec8*)&bAl[r * BKt + (cs0 ^ (kk * 32))];
        }
      __builtin_amdgcn_s_setprio(1);
#pragma unroll
      for (int jj = 0; jj < 4; ++jj)
#pragma unroll
        for (int ii = 0; ii < 2; ++ii)
#pragma unroll
          for (int kk = 0; kk < KK; ++kk) {
            acc[mq * 2 + ii][jj] =
                mfma8(af[kk][ii], bf[kk][jj], acc[mq * 2 + ii][jj]);
            if constexpr (AT == 2)
              acc[mq * 2 + ii][jj] =
                  mfma8(alf[kk][ii], bf[kk][jj], acc[mq * 2 + ii][jj]);
          }
      __builtin_amdgcn_s_setprio(0);
    }
  };

  stage(0, 0);
  stage(1, 1);
  vwait<LPT>();
  block_bar();

  for (int t = 0; t < NT; ++t) {
    const int cur = t & 1;
    compute(cur);
    if (t + 1 < NT) {
      block_bar();
      if (t + 2 < NT) {
        stage(cur, t + 2);
        vwait<LPT>();
      } else {
        vwait<0>();
      }
      block_bar();
    }
  }

  if constexpr (EPI == EPI_F16) {
    TO* Ch = (TO*)C0;
#pragma unroll
    for (int i = 0; i < MF; ++i) {
      const int mb = bm + wm + i * 16 + quad * 4;
#pragma unroll
      for (int j = 0; j < 4; ++j) {
        const int n = bn + wn + j * 16 + l16;
#pragma unroll
        for (int r = 0; r < 4; ++r)
          Ch[(long)(mb + r) * ldc + n] = (TO)acc[i][j][r];
      }
    }
  } else if constexpr (EPI == EPI_VT) {
    TO* vT = (TO*)C0;
#pragma unroll
    for (int i = 0; i < MF; ++i) {
      const int mb = bm + wm + i * 16 + quad * 4;
      const long bb = mb >> 11;
      const long ml = mb & 2047;
#pragma unroll
      for (int j = 0; j < 4; ++j) {
        const int e = bn + wn + j * 16 + l16;
        union { TO b[4]; uint2 u; } P;
#pragma unroll
        for (int r = 0; r < 4; ++r) P.b[r] = (TO)acc[i][j][r];
        *(uint2*)&vT[(bb * 768 + e) * 2048 + ml] = P.u;
      }
    }
  } else {  // EPI_F32
    float* C = (float*)C0 + (long)z * stC;
#pragma unroll
    for (int i = 0; i < MF; ++i) {
      const int mb = bm + wm + i * 16 + quad * 4;
#pragma unroll
      for (int j = 0; j < 4; ++j) {
        const int n = bn + wn + j * 16 + l16;
#pragma unroll
        for (int r = 0; r < 4; ++r)
          C[(long)(mb + r) * ldc + n] = acc[i][j][r];
      }
    }
  }
}

// ---------------------------------------------------------------------------
// Old 128x128/BK64 drain kernel (verified) — kept for the small Mt GEMM only.
// ---------------------------------------------------------------------------
constexpr int BM = 128, BN = 128, BK = 64;

template <typename T, typename TO, int AT, int BT, int EPI, int SWZ>
__global__ __launch_bounds__(256)
void gemm_kernel(const T* __restrict__ Ah, const T* __restrict__ Al,
                 const T* __restrict__ Bh, const T* __restrict__ Bl,
                 void* __restrict__ C0, void* __restrict__ C1,
                 int K, long lda, long ldb, long ldbl, long ldc,
                 long stA, long stB, long stBl, long stC,
                 int gxN, int gyM) {
  using vec8 = typename std::conditional<std::is_same<T, bf16>::value,
                                         bf16x8, f16x8>::type;
  __shared__ __align__(16) T sAh[BM * BK];
  __shared__ __align__(16) T sBh[BN * BK];
  __shared__ __align__(16) T sAl[AT == 2 ? BM * BK : 8];
  __shared__ __align__(16) T sBl[BT == 2 ? BN * BK : 8];

  int bxi, byi, z;
  if constexpr (SWZ) {
    const int id = blockIdx.x;
    const int xcd = id & 7;
    const int j = id >> 3;
    const int s = j / gxN;
    const int n = j - s * gxN;
    const int g = xcd + 8 * s;
    bxi = n;
    byi = g % gyM;
    z = g / gyM;
  } else {
    bxi = blockIdx.x; byi = blockIdx.y; z = blockIdx.z;
  }

  const T* pAh = Ah + (long)z * stA;
  const T* pBh = Bh + (long)z * stB;
  const T* pAl = (AT == 2) ? (Al + (long)z * stA) : nullptr;
  const T* pBl = (BT == 2) ? (Bl + (long)z * stBl) : nullptr;

  const int bm = byi * BM;
  const int bn = bxi * BN;
  const int tid = threadIdx.x;
  const int wave = tid >> 6;
  const int lane = tid & 63;
  const int wm = (wave & 1) * 64;
  const int wn = (wave >> 1) * 64;
  const int quad = lane >> 4;
  const int l16 = lane & 15;

  f32x4 acc[4][4] = {};

  const int sr0 = tid >> 3;
  const int swc = ((tid & 7) ^ (sr0 & 7)) * 8;
  const int cs0 = (quad * 8) ^ ((l16 & 7) << 3);

  for (int kt = 0; kt < K; kt += BK) {
    __syncthreads();
    {
      const long ka = kt + swc;
#pragma unroll
      for (int l = 0; l < 4; ++l) {
        const int row = l * 32 + sr0;
        async16(pAh + (long)(bm + row) * lda + ka, &sAh[(l * 256 + tid) * 8]);
      }
#pragma unroll
      for (int l = 0; l < 4; ++l) {
        const int row = l * 32 + sr0;
        async16(pBh + (long)(bn + row) * ldb + ka, &sBh[(l * 256 + tid) * 8]);
      }
      if constexpr (AT == 2) {
#pragma unroll
        for (int l = 0; l < 4; ++l) {
          const int row = l * 32 + sr0;
          async16(pAl + (long)(bm + row) * lda + ka, &sAl[(l * 256 + tid) * 8]);
        }
      }
      if constexpr (BT == 2) {
#pragma unroll
        for (int l = 0; l < 4; ++l) {
          const int row = l * 32 + sr0;
          async16(pBl + (long)(bn + row) * ldbl + ka, &sBl[(l * 256 + tid) * 8]);
        }
      }
    }
    __syncthreads();

#pragma unroll
    for (int kk = 0; kk < 2; ++kk) {
      const int cs = cs0 ^ (kk * 32);
      vec8 ah[4], al[4];
#pragma unroll
      for (int i = 0; i < 4; ++i) {
        ah[i] = *(const vec8*)&sAh[(wm + i * 16 + l16) * BK + cs];
        if constexpr (AT == 2)
          al[i] = *(const vec8*)&sAl[(wm + i * 16 + l16) * BK + cs];
      }
#pragma unroll
      for (int j = 0; j < 4; ++j) {
        const vec8 bh = *(const vec8*)&sBh[(wn + j * 16 + l16) * BK + cs];
        vec8 bl;
        if constexpr (BT == 2)
          bl = *(const vec8*)&sBl[(wn + j * 16 + l16) * BK + cs];
#pragma unroll
        for (int i = 0; i < 4; ++i) {
          acc[i][j] = mfma8(ah[i], bh, acc[i][j]);
          if constexpr (BT == 2) acc[i][j] = mfma8(ah[i], bl, acc[i][j]);
          if constexpr (AT == 2) acc[i][j] = mfma8(al[i], bh, acc[i][j]);
        }
      }
    }
  }

  if constexpr (EPI == EPI_PAIR) {
    TO* Ch = (TO*)C0;
    TO* Cl = (TO*)C1;
#pragma unroll
    for (int i = 0; i < 4; ++i) {
      const int mb = bm + wm + i * 16 + quad * 4;
#pragma unroll
      for (int j = 0; j < 4; ++j) {
        const int n = bn + wn + j * 16 + l16;
#pragma unroll
        for (int r = 0; r < 4; ++r) {
          const float f = acc[i][j][r];
          const TO h = (TO)f;
          const long idx = (long)(mb + r) * ldc + n;
          Ch[idx] = h;
          Cl[idx] = (TO)(f - (float)h);
        }
      }
    }
  }
}

// One block per score row (2048 fp32). Writes normalized p * (1/sqrt(768)) as
// f16 IN-PLACE into the first quarter of the row's fp32 storage.
__global__ __launch_bounds__(256)
void softmax_kernel(float* __restrict__ sc) {
  __shared__ float red[4];
  float* srow = sc + (long)blockIdx.x * 2048;
  const int tid = threadIdx.x;
  const int wave = tid >> 6;
  const int lane = tid & 63;
  const float4 v0 = *(const float4*)(srow + tid * 4);
  const float4 v1 = *(const float4*)(srow + 1024 + tid * 4);
  float mx = fmaxf(fmaxf(fmaxf(v0.x, v0.y), fmaxf(v0.z, v0.w)),
                   fmaxf(fmaxf(v1.x, v1.y), fmaxf(v1.z, v1.w)));
#pragma unroll
  for (int o = 32; o >= 1; o >>= 1) mx = fmaxf(mx, __shfl_xor(mx, o));
  if (lane == 0) red[wave] = mx;
  __syncthreads();
  mx = fmaxf(fmaxf(red[0], red[1]), fmaxf(red[2], red[3]));
  const float e0 = exp2f((v0.x - mx) * LOG2E);
  const float e1 = exp2f((v0.y - mx) * LOG2E);
  const float e2 = exp2f((v0.z - mx) * LOG2E);
  const float e3 = exp2f((v0.w - mx) * LOG2E);
  const float e4 = exp2f((v1.x - mx) * LOG2E);
  const float e5 = exp2f((v1.y - mx) * LOG2E);
  const float e6 = exp2f((v1.z - mx) * LOG2E);
  const float e7 = exp2f((v1.w - mx) * LOG2E);
  float s = ((e0 + e1) + (e2 + e3)) + ((e4 + e5) + (e6 + e7));
#pragma unroll
  for (int o = 32; o >= 1; o >>= 1) s += __shfl_xor(s, o);
  __syncthreads();
  if (lane == 0) red[wave] = s;
  __syncthreads();
  s = red[0] + red[1] + red[2] + red[3];
  const float inv = 1.0f / (s * SQRT_E);
  f16* prow = (f16*)srow;
  union { f16 b[4]; uint2 u; } P;
  P.b[0] = (f16)(e0 * inv); P.b[1] = (f16)(e1 * inv);
  P.b[2] = (f16)(e2 * inv); P.b[3] = (f16)(e3 * inv);
  *(uint2*)(prow + tid * 4) = P.u;
  P.b[0] = (f16)(e4 * inv); P.b[1] = (f16)(e5 * inv);
  P.b[2] = (f16)(e6 * inv); P.b[3] = (f16)(e7 * inv);
  *(uint2*)(prow + 1024 + tid * 4) = P.u;
}

// Fused fp32 -> f16: x -> hi/lo pair; Wv -> single.
__global__ __launch_bounds__(256)
void split_all(const float4* __restrict__ x, const float4* __restrict__ wv,
               uint2* __restrict__ xh, uint2* __restrict__ xl,
               uint2* __restrict__ wvh) {
  constexpr int NX = 3145728;
  constexpr int NWV = 147456;
  const int i = blockIdx.x * 256 + threadIdx.x;
  float4 v;
  uint2 *dh, *dl;
  if (i < NX) {
    v = x[i]; dh = xh + i; dl = xl + i;
  } else {
    const int m = i - NX;
    if (m >= NWV) return;
    v = wv[m]; dh = wvh + m; dl = nullptr;
  }
  const f16 h0 = (f16)v.x, h1 = (f16)v.y, h2 = (f16)v.z, h3 = (f16)v.w;
  union { f16 b[4]; uint2 u; } P;
  P.b[0] = h0; P.b[1] = h1; P.b[2] = h2; P.b[3] = h3;
  *dh = P.u;
  if (dl != nullptr) {
    P.b[0] = (f16)(v.x - (float)h0);
    P.b[1] = (f16)(v.y - (float)h1);
    P.b[2] = (f16)(v.z - (float)h2);
    P.b[3] = (f16)(v.w - (float)h3);
    *dl = P.u;
  }
}

// Transpose 768x768 fp32 W[e][d] -> f16 hi/lo pair WT[d][e] (e contiguous).
__global__ __launch_bounds__(256)
void transpose_split(const float* __restrict__ Wq, const float* __restrict__ Wk,
                     f16* __restrict__ qTh, f16* __restrict__ qTl,
                     f16* __restrict__ kTh, f16* __restrict__ kTl) {
  __shared__ float tile[64][65];
  const float* src = blockIdx.z ? Wk : Wq;
  f16* dh = blockIdx.z ? kTh : qTh;
  f16* dl = blockIdx.z ? kTl : qTl;
  const int e0 = blockIdx.y * 64, d0 = blockIdx.x * 64;
  const int t = threadIdx.x;
  const int r = t >> 2;
  const int c4 = (t & 3) * 16;
  const float4* s4 = (const float4*)(src + (long)(e0 + r) * 768 + d0 + c4);
#pragma unroll
  for (int g = 0; g < 4; ++g) {
    const float4 v = s4[g];
    tile[r][c4 + g * 4 + 0] = v.x;
    tile[r][c4 + g * 4 + 1] = v.y;
    tile[r][c4 + g * 4 + 2] = v.z;
    tile[r][c4 + g * 4 + 3] = v.w;
  }
  __syncthreads();
  union { f16 b[8]; uint4 u; } H0, H1, L0, L1;
#pragma unroll
  for (int i = 0; i < 16; ++i) {
    const float v = tile[c4 + i][r];
    const f16 h = (f16)v;
    const f16 l = (f16)(v - (float)h);
    if (i < 8) { H0.b[i] = h; L0.b[i] = l; }
    else       { H1.b[i - 8] = h; L1.b[i - 8] = l; }
  }
  const long o = (long)(d0 + r) * 768 + e0 + c4;
  *(uint4*)(dh + o) = H0.u;  *(uint4*)(dh + o + 8) = H1.u;
  *(uint4*)(dl + o) = L0.u;  *(uint4*)(dl + o + 8) = L1.u;
}

extern "C" void kernel_launch(void* const* d_in, const int* in_sizes, int n_in,
                              void* d_out, int out_size, void* d_ws, size_t ws_size,
                              hipStream_t stream) {
  const float* x  = (const float*)d_in[0];
  const float* Wq = (const float*)d_in[1];
  const float* Wk = (const float*)d_in[2];
  const float* Wv = (const float*)d_in[3];
  float* out = (float*)d_out;
  char* ws = (char*)d_ws;

  // ---- workspace layout (bytes) ----
  const size_t SZ = 25165824;      // 16384*768*2
  f16* yh = (f16*)(ws + 0 * SZ);
  f16* xh = (f16*)(ws + 2 * SZ);
  f16* vT = (f16*)(ws + 3 * SZ);
  const size_t PERS = 4 * SZ;      // 100663296
  const size_t WT = 1179648;       // 768*768 f16
  f16* xl   = (f16*)(ws + PERS);
  f16* wqTh = (f16*)(ws + PERS + SZ);
  f16* wqTl = (f16*)(ws + PERS + SZ + 1 * WT);
  f16* wkTh = (f16*)(ws + PERS + SZ + 2 * WT);
  f16* wkTl = (f16*)(ws + PERS + SZ + 3 * WT);
  f16* mtH  = (f16*)(ws + PERS + SZ + 4 * WT);
  f16* mtL  = (f16*)(ws + PERS + SZ + 5 * WT);
  f16* wvh  = (f16*)(ws + PERS + SZ + 6 * WT);
  float* scores = (float*)(ws + PERS);

  long avail = (long)ws_size - (long)PERS;
  int nb = (int)(avail / 16777216);
  if (nb < 1) nb = 1;
  if (nb > 8) nb = 8;

  // ---- phase 1 ----
  split_all<<<12864, 256, 0, stream>>>(
      (const float4*)x, (const float4*)Wv, (uint2*)xh, (uint2*)xl, (uint2*)wvh);
  transpose_split<<<dim3(12, 12, 2), 256, 0, stream>>>(
      Wq, Wk, wqTh, wqTl, wkTh, wkTl);

  // M^T[d'][d] = sum_e WkT[d'][e] * WqT[d][e]  (3-term, f16 pair out)
  gemm_kernel<f16, f16, 2, 2, EPI_PAIR, 0><<<dim3(6, 6, 1), 256, 0, stream>>>(
      wkTh, wkTl, wqTh, wqTl, (void*)mtH, (void*)mtL,
      768, 768, 768, 768, 768, 0, 0, 0, 0, 0, 0);

  // y = (xh+xl) * MT_h^T : f16 hi only, 2-term, BK32 dbuf
  gemm_pipe<f16, f16, 128, 128, 32, 2, EPI_F16><<<768, 256, 0, stream>>>(
      xh, xl, mtH, (void*)yh, 768, 768, 768, 768, 0, 0, 0, 6, 128);

  // v = xh * Wv_h^T -> vT f16 transposed, 1-term, BK64 dbuf
  gemm_pipe<f16, f16, 128, 128, 64, 1, EPI_VT><<<768, 256, 0, stream>>>(
      xh, nullptr, wvh, (void*)vT, 768, 768, 768, 0, 0, 0, 0, 6, 128);

  // ---- phase 2: scores -> softmax -> PV ----
  const long RS = 1572864;   // 2048*768
  const long VTS = 1572864;  // 768*2048
  for (int b0 = 0; b0 < 8; b0 += nb) {
    const int nbg = (8 - b0 < nb) ? (8 - b0) : nb;
    // S = yh * xh^T : 256^2 ring, z-major (one batch per XCD)
    gemm_ring<f16, float, 1, EPI_F32><<<64 * nbg, 512, 0, stream>>>(
        yh + (long)b0 * RS, nullptr, xh + (long)b0 * RS, (void*)scores,
        768, 768, 768, 2048, RS, RS, 4194304L, 8, 8, nbg);
    softmax_kernel<<<nbg * 2048, 256, 0, stream>>>(scores);
    // O = P * vT^T : 256^2 ring (P f16 rows in fp32 score rows, pitch 4096)
    gemm_ring<f16, float, 1, EPI_F32><<<24 * nbg, 512, 0, stream>>>(
        (const f16*)scores, nullptr, vT + (long)b0 * VTS,
        (void*)(out + (long)b0 * 1572864),
        2048, 4096, 2048, 768, 8388608L, VTS, 1572864L, 3, 8, nbg);
  }
}